// Round 4
// 1432.168 us; speedup vs baseline: 1.0160x; 1.0160x over previous
//
#include <hip/hip_runtime.h>
#include <hip/hip_bf16.h>
#include <cstdint>
#include <cstddef>

typedef _Float16 half8  __attribute__((ext_vector_type(8)));
typedef float    floatx4 __attribute__((ext_vector_type(4)));
typedef int      int4v   __attribute__((ext_vector_type(4)));

#define S_LEN 200
#define BATCH 2048
#define HID   128
#define T_LEN 50
#define IN_D  44

// Sentinel: two f16 NaNs. h/FC values are finite => data dword never equals it.
#define SENT32 0x7E007E00

// ---- workspace byte offsets ----
#define OFF_ENCW   0ull
#define OFF_DECW   983040ull
#define OFF_RING_E 1978368ull    // [3][8][2048][128] f16 = 12,582,912 B
#define OFF_RING_D 14561280ull   // [3][4][2048][128] f16 = 6,291,456 B
#define OFF_ORING  20852736ull   // [4][2048][64] f16 = 1,048,576 B
#define OFF_HENC   21901312ull   // [4][2048][128] f16 = 2,097,152 B
#define OFF_CENC   23998464ull   // [4][2048][128] f32 = 4,194,304 B
#define OFF_FLAGS  28192768ull   // int[1024*32]: flag i at [i*32]
// rings contiguous: 19,922,944 B = 4,980,736 dwords

#define SCOPE_AGENT __HIP_MEMORY_SCOPE_AGENT

#define LOG2E  1.44269504f
#define LOG2E2 2.88539008f
__device__ __forceinline__ float sigf(float x){
  float e = __builtin_amdgcn_exp2f(-LOG2E * x);
  return __builtin_amdgcn_rcpf(1.f + e);
}
__device__ __forceinline__ float tanhf_fast(float x){
  float e = __builtin_amdgcn_exp2f(LOG2E2 * x);
  return 1.f - 2.f * __builtin_amdgcn_rcpf(e + 1.f);
}

__device__ __forceinline__ int  ldc(const int* p){ return __hip_atomic_load(p, __ATOMIC_RELAXED, SCOPE_AGENT); }
__device__ __forceinline__ void stc(int* p, int v){ __hip_atomic_store(p, v, __ATOMIC_RELAXED, SCOPE_AGENT); }
__device__ __forceinline__ void drain_vm(){ asm volatile("s_waitcnt vmcnt(0)" ::: "memory"); }
__device__ __forceinline__ int* flagp(int* flags, int idx){ return flags + idx*32; }

// ---- self-contained x4 fabric ops (sc0 sc1 = L1/L2 bypass, MALL-coherent).
// Load embeds its own vmcnt(0): value is architecturally valid at asm exit —
// NO issue-only register hazard (the round-1/2 prefetch construct is gone).
__device__ __forceinline__ int4v ld_ring_x4(const int* p){
  int4v r;
  asm volatile("global_load_dwordx4 %0, %1, off sc0 sc1\n\t"
               "s_waitcnt vmcnt(0)"
               : "=v"(r) : "v"(p) : "memory");
  return r;
}
__device__ __forceinline__ void st_ring_x4(int* p, int4v v){
  asm volatile("global_store_dwordx4 %0, %1, off sc0 sc1"
               :: "v"(p), "v"(v) : "memory");
}
__device__ __forceinline__ bool any_sent(int4v v){
  return (v.x==SENT32)||(v.y==SENT32)||(v.z==SENT32)||(v.w==SENT32);
}

#define PIN(v) asm volatile("" : "+v"(v))

__global__ void prep_weights(const float* __restrict__ eW0, const float* __restrict__ eWR,
                             const float* __restrict__ eWH, const float* __restrict__ dW0,
                             const float* __restrict__ dWR, const float* __restrict__ dWH,
                             const float* __restrict__ fcW,
                             _Float16* __restrict__ encw, _Float16* __restrict__ decw,
                             int* __restrict__ rings, int* __restrict__ flags)
{
  int i = blockIdx.x*256 + threadIdx.x;
  if (i < 491520) {
    _Float16 v;
    if (i < 32768)      { int j=i>>6, k=i&63; v = (k<IN_D)? (_Float16)eW0[j*IN_D+k] : (_Float16)0.f; }
    else if (i < 229376){ v = (_Float16)eWR[i-32768]; }
    else                { v = (_Float16)eWH[i-229376]; }
    encw[i] = v;
  }
  if (i < 497664) {
    _Float16 v;
    if (i < 32768)      { int j=i>>6, k=i&63; v = (k<IN_D)? (_Float16)dW0[j*IN_D+k] : (_Float16)0.f; }
    else if (i < 229376){ v = (_Float16)dWR[i-32768]; }
    else if (i < 491520){ v = (_Float16)dWH[i-229376]; }
    else { int r=i-491520; int j=r>>7, k=r&127; v = (j<IN_D)? (_Float16)fcW[j*HID+k] : (_Float16)0.f; }
    decw[i] = v;
  }
  for (int j = i; j < 4980736; j += 4096*256) rings[j] = SENT32;  // sentinel-fill all rings
  if (i < 32768) flags[i] = 0;
}

// ============================================================================
// enc_pipe: BYTE-IDENTICAL to the verified 1452 µs baseline (bisection arm A).
// ============================================================================

__global__ __launch_bounds__(512, 2)
void enc_pipe(const float* __restrict__ x, const _Float16* __restrict__ encw,
              const float* __restrict__ enc_b, _Float16* __restrict__ ring,
              _Float16* __restrict__ h_enc, float* __restrict__ c_enc,
              int* __restrict__ flags)
{
  const int tid = threadIdx.x;
  const int w = tid >> 6, lane = tid & 63, quad = lane >> 4, n16 = lane & 15;
  const int l = blockIdx.x >> 6, s = blockIdx.x & 63, r0 = s * 32;
  const int u = w*16 + n16;
  const int KSI = (l == 0) ? 2 : 4;

  __shared__ _Float16 xbuf[32][136];
  __shared__ _Float16 hb[2][32][136];

  for (int i = tid; i < 32*136; i += 512){
    ((_Float16*)xbuf)[i] = (_Float16)0.f;
    ((_Float16*)hb[0])[i] = (_Float16)0.f;
  }

  const _Float16* Wi = (l==0) ? encw : encw + 32768 + (size_t)(l-1)*65536;
  const _Float16* Wh = encw + 229376 + (size_t)l*65536;
  const int KI = KSI * 32;
  floatx4 wfi[4][4], wfh[4][4];
  #pragma unroll
  for (int nt = 0; nt < 4; ++nt){
    const int grow = nt*128 + u;
    #pragma unroll
    for (int ks = 0; ks < 4; ++ks){
      if (ks < KSI){ wfi[nt][ks] = *(const floatx4*)(Wi + (size_t)grow*KI + ks*32 + quad*8); PIN(wfi[nt][ks]); }
      wfh[nt][ks] = *(const floatx4*)(Wh + (size_t)grow*HID + ks*32 + quad*8); PIN(wfh[nt][ks]);
    }
  }
  float breg[4];
  #pragma unroll
  for (int g = 0; g < 4; ++g) breg[g] = enc_b[l*512 + g*128 + u];
  float creg[2][4] = {{0.f,0.f,0.f,0.f},{0.f,0.f,0.f,0.f}};

  // layer-0 x prefetch (3 elems/thread covers 32*44=1408)
  int xr_r[3], xr_k[3]; bool xr_v[3]; float xr[3];
  if (l == 0){
    #pragma unroll
    for (int j = 0; j < 3; ++j){
      int idx = tid + j*512; xr_v[j] = idx < 32*IN_D;
      xr_r[j] = xr_v[j] ? idx / IN_D : 0; xr_k[j] = xr_v[j] ? idx % IN_D : 0;
      xr[j] = xr_v[j] ? x[((size_t)(r0+xr_r[j])*S_LEN + 0)*IN_D + xr_k[j]] : 0.f;
    }
  }

  int* cflag_self = flagp(flags, l*64 + s);        // published by l>=1
  int* cflag_next = flagp(flags, (l+1)*64 + s);    // read by l<3 (backpressure)
  int seen_cons = 0;

  __syncthreads();

  _Float16 (*hcur)[136] = hb[0];
  _Float16 (*hnxt)[136] = hb[1];

  const int d0 = tid, d1 = tid+512, d2 = tid+1024, d3 = tid+1536;

  for (int t = 0; t < S_LEN; ++t){
    // ---- stage input (data-as-flag poll for l>0) ----
    if (l == 0){
      #pragma unroll
      for (int j = 0; j < 3; ++j)
        if (xr_v[j]) xbuf[xr_r[j]][xr_k[j]] = (_Float16)xr[j];
    } else {
      int* srcd = (int*)(ring + (((size_t)(l-1)*8 + (t&7))*BATCH + r0)*HID);
      int v0 = ldc(srcd+d0), v1 = ldc(srcd+d1), v2 = ldc(srcd+d2), v3 = ldc(srcd+d3);
      while (v0==SENT32 || v1==SENT32 || v2==SENT32 || v3==SENT32){
        if (v0==SENT32) v0 = ldc(srcd+d0);
        if (v1==SENT32) v1 = ldc(srcd+d1);
        if (v2==SENT32) v2 = ldc(srcd+d2);
        if (v3==SENT32) v3 = ldc(srcd+d3);
      }
      *(int*)&xbuf[d0>>6][(d0&63)*2] = v0;
      *(int*)&xbuf[d1>>6][(d1&63)*2] = v1;
      *(int*)&xbuf[d2>>6][(d2&63)*2] = v2;
      *(int*)&xbuf[d3>>6][(d3&63)*2] = v3;
      stc(srcd+d0, SENT32); stc(srcd+d1, SENT32);
      stc(srcd+d2, SENT32); stc(srcd+d3, SENT32);
    }
    // backpressure (slow path; depth-8 ring => nearly always cached-skip)
    if (tid == 0 && l < 3 && t >= 8){
      while (seen_cons < t-7){
        seen_cons = ldc(cflag_next);
        if (seen_cons < t-7) __builtin_amdgcn_s_sleep(1);
      }
    }
    __syncthreads();

    if (l == 0 && t < S_LEN-1){
      #pragma unroll
      for (int j = 0; j < 3; ++j)
        if (xr_v[j]) xr[j] = x[((size_t)(r0+xr_r[j])*S_LEN + (t+1))*IN_D + xr_k[j]];
    }

    // ---- gates via MFMA + in-register cell update ----
    #pragma unroll
    for (int m = 0; m < 2; ++m){
      half8 ai[4], ah[4];
      #pragma unroll
      for (int ks = 0; ks < 4; ++ks){
        if (ks < KSI) ai[ks] = *(const half8*)&xbuf[m*16+n16][ks*32 + quad*8];
        ah[ks] = *(const half8*)&hcur[m*16+n16][ks*32 + quad*8];
      }
      floatx4 acc[4];
      #pragma unroll
      for (int nt = 0; nt < 4; ++nt){
        acc[nt] = (floatx4){0.f,0.f,0.f,0.f};
        #pragma unroll
        for (int ks = 0; ks < 4; ++ks){
          if (ks < KSI) acc[nt] = __builtin_amdgcn_mfma_f32_16x16x32_f16(ai[ks], __builtin_bit_cast(half8, wfi[nt][ks]), acc[nt], 0,0,0);
          acc[nt] = __builtin_amdgcn_mfma_f32_16x16x32_f16(ah[ks], __builtin_bit_cast(half8, wfh[nt][ks]), acc[nt], 0,0,0);
        }
      }
      #pragma unroll
      for (int rr = 0; rr < 4; ++rr){
        float ip = acc[0][rr] + breg[0];
        float fp = acc[1][rr] + breg[1];
        float gp = acc[2][rr] + breg[2];
        float op = acc[3][rr] + breg[3];
        float cc = sigf(fp)*creg[m][rr] + sigf(ip)*tanhf_fast(gp);
        float hh = sigf(op)*tanhf_fast(cc);
        creg[m][rr] = cc;
        const int row = m*16 + quad*4 + rr;
        hnxt[row][u] = (_Float16)hh;
        if (t == S_LEN-1){
          h_enc[((size_t)l*BATCH + r0 + row)*HID + u] = (_Float16)hh;
          c_enc[((size_t)l*BATCH + r0 + row)*HID + u] = cc;
        }
      }
    }
    __syncthreads();

    // consumed-flag publish (sentinel-resets had the whole compute to land)
    if (l > 0){
      drain_vm();
      if (tid == 0) stc(cflag_self, t+1);
    }
    // ---- publish h: data IS the flag; no drain needed ----
    if (l < 3){
      int* dst = (int*)(ring + (((size_t)l*8 + (t&7))*BATCH + r0)*HID);
      stc(dst+d0, *(const int*)&hnxt[d0>>6][(d0&63)*2]);
      stc(dst+d1, *(const int*)&hnxt[d1>>6][(d1&63)*2]);
      stc(dst+d2, *(const int*)&hnxt[d2>>6][(d2&63)*2]);
      stc(dst+d3, *(const int*)&hnxt[d3>>6][(d3&63)*2]);
    }
    _Float16 (*tmp)[136] = hcur; hcur = hnxt; hnxt = tmp;
  }
}

// ============================================================================
// dec_pipe (bisection arm B): FULL baseline protocol — backpressure flags,
// drain_vm before consumed-flag publish, tracked flag stores — with ONLY the
// ring polls/resets/publishes widened to x4 asm ops. The drain_vm's HW
// vmcnt(0) counts asm stores too, so the reset-before-flag invariant holds.
// ============================================================================

__global__ __launch_bounds__(512, 2)
void dec_pipe(const float* __restrict__ x, const _Float16* __restrict__ decw,
              const float* __restrict__ dec_b, const float* __restrict__ fc_b,
              _Float16* __restrict__ ring, _Float16* __restrict__ oring,
              const _Float16* __restrict__ h_enc, const float* __restrict__ c_enc,
              int* __restrict__ flags, float* __restrict__ out)
{
  const int tid = threadIdx.x;
  const int w = tid >> 6, lane = tid & 63, quad = lane >> 4, n16 = lane & 15;
  const int l = blockIdx.x >> 6, s = blockIdx.x & 63, r0 = s * 32;
  const int u = w*16 + n16;
  const int KSI = (l == 0) ? 2 : 4;
  const int my4 = tid*4;

  __shared__ _Float16 xbuf[32][136];
  __shared__ _Float16 hb[2][32][136];
  __shared__ _Float16 fcout[32][64];

  for (int i = tid; i < 32*136; i += 512) ((_Float16*)xbuf)[i] = (_Float16)0.f;
  for (int i = tid; i < 32*64; i += 512) ((_Float16*)fcout)[i] = (_Float16)0.f;

  const _Float16* Wi = (l==0) ? decw : decw + 32768 + (size_t)(l-1)*65536;
  const _Float16* Wh = decw + 229376 + (size_t)l*65536;
  const _Float16* FCW = decw + 491520;
  const int KI = KSI * 32;
  floatx4 wfi[4][4], wfh[4][4];
  #pragma unroll
  for (int nt = 0; nt < 4; ++nt){
    const int grow = nt*128 + u;
    #pragma unroll
    for (int ks = 0; ks < 4; ++ks){
      if (ks < KSI){ wfi[nt][ks] = *(const floatx4*)(Wi + (size_t)grow*KI + ks*32 + quad*8); PIN(wfi[nt][ks]); }
      wfh[nt][ks] = *(const floatx4*)(Wh + (size_t)grow*HID + ks*32 + quad*8); PIN(wfh[nt][ks]);
    }
  }
  float breg[4];
  #pragma unroll
  for (int g = 0; g < 4; ++g) breg[g] = dec_b[l*512 + g*128 + u];

  {
    int idx = tid*8, rr_ = idx >> 7, kk = idx & 127;
    *(half8*)&hb[0][rr_][kk] = *(const half8*)(h_enc + ((size_t)l*BATCH + r0)*HID + rr_*HID + kk);
  }
  float creg[2][4];
  #pragma unroll
  for (int m = 0; m < 2; ++m)
    #pragma unroll
    for (int rr = 0; rr < 4; ++rr)
      creg[m][rr] = c_enc[((size_t)l*BATCH + r0 + m*16 + quad*4 + rr)*HID + u];

  floatx4 wfc[4]; float fcb_j = 0.f;
  const int j = w*16 + n16;
  if (w < 3){
    #pragma unroll
    for (int ks = 0; ks < 4; ++ks){
      wfc[ks] = *(const floatx4*)(FCW + (size_t)j*HID + ks*32 + quad*8); PIN(wfc[ks]);
    }
    if (j < IN_D) fcb_j = fc_b[j];
  }

  int* cflag_self = flagp(flags, 256 + l*64 + s);     // published by l>=1 (ring_d)
  int* cflag_next = flagp(flags, 256 + (l+1)*64 + s); // read by l<3
  int* cflag_o    = flagp(flags, 512 + s);            // published by l0, read by l3
  int seen = 0;

  __syncthreads();

  _Float16 (*hcur)[136] = hb[0];
  _Float16 (*hnxt)[136] = hb[1];

  const int4v sv = {SENT32, SENT32, SENT32, SENT32};

  for (int t = 0; t < T_LEN; ++t){
    // ---- stage input (x4 polls, embedded vmcnt(0)) ----
    if (l == 0){
      if (t == 0){
        for (int idx = tid; idx < 32*IN_D; idx += 512){
          int r = idx / IN_D, k = idx % IN_D;
          xbuf[r][k] = (_Float16)x[((size_t)(r0+r)*S_LEN + (S_LEN-1))*IN_D + k];
        }
      } else if (tid < 256){
        int* srcd = (int*)(oring + (((size_t)((t-1)&3))*BATCH + r0)*64);
        int4v v = ld_ring_x4(srcd + my4);
        while (any_sent(v)){
          __builtin_amdgcn_s_sleep(1);
          v = ld_ring_x4(srcd + my4);
        }
        *(int4v*)&xbuf[my4>>5][(my4&31)*2] = v;
        st_ring_x4(srcd + my4, sv);
      }
    } else {
      int* srcd = (int*)(ring + (((size_t)(l-1)*4 + (t&3))*BATCH + r0)*HID);
      int4v v = ld_ring_x4(srcd + my4);
      while (any_sent(v)){
        __builtin_amdgcn_s_sleep(1);
        v = ld_ring_x4(srcd + my4);
      }
      *(int4v*)&xbuf[my4>>6][(my4&63)*2] = v;
      st_ring_x4(srcd + my4, sv);
    }
    // backpressure (slow path) — exact baseline
    if (tid == 0 && t >= 4){
      if (l < 3){
        while (seen < t-3){ seen = ldc(cflag_next); if (seen < t-3) __builtin_amdgcn_s_sleep(1); }
      } else {
        while (seen < t-2){ seen = ldc(cflag_o); if (seen < t-2) __builtin_amdgcn_s_sleep(1); }
      }
    }
    __syncthreads();

    // ---- gates + cell update ----
    #pragma unroll
    for (int m = 0; m < 2; ++m){
      half8 ai[4], ah[4];
      #pragma unroll
      for (int ks = 0; ks < 4; ++ks){
        if (ks < KSI) ai[ks] = *(const half8*)&xbuf[m*16+n16][ks*32 + quad*8];
        ah[ks] = *(const half8*)&hcur[m*16+n16][ks*32 + quad*8];
      }
      floatx4 acc[4];
      #pragma unroll
      for (int nt = 0; nt < 4; ++nt){
        acc[nt] = (floatx4){0.f,0.f,0.f,0.f};
        #pragma unroll
        for (int ks = 0; ks < 4; ++ks){
          if (ks < KSI) acc[nt] = __builtin_amdgcn_mfma_f32_16x16x32_f16(ai[ks], __builtin_bit_cast(half8, wfi[nt][ks]), acc[nt], 0,0,0);
          acc[nt] = __builtin_amdgcn_mfma_f32_16x16x32_f16(ah[ks], __builtin_bit_cast(half8, wfh[nt][ks]), acc[nt], 0,0,0);
        }
      }
      #pragma unroll
      for (int rr = 0; rr < 4; ++rr){
        float ip = acc[0][rr] + breg[0];
        float fp = acc[1][rr] + breg[1];
        float gp = acc[2][rr] + breg[2];
        float op = acc[3][rr] + breg[3];
        float cc = sigf(fp)*creg[m][rr] + sigf(ip)*tanhf_fast(gp);
        float hh = sigf(op)*tanhf_fast(cc);
        creg[m][rr] = cc;
        hnxt[m*16 + quad*4 + rr][u] = (_Float16)hh;
      }
    }
    __syncthreads();

    // consumed-flag publish — exact baseline (drain covers asm resets: HW counter)
    drain_vm();
    if (tid == 0){
      if (l > 0) stc(cflag_self, t+1);
      else if (t > 0) stc(cflag_o, t+1);
    }

    if (l < 3){
      int* dst = (int*)(ring + (((size_t)l*4 + (t&3))*BATCH + r0)*HID);
      st_ring_x4(dst + my4, *(const int4v*)&hnxt[my4>>6][(my4&63)*2]);
    } else {
      // ---- FC + output + feedback (waves 0..2 cover cols 0..47) ----
      if (w < 3){
        #pragma unroll
        for (int m = 0; m < 2; ++m){
          half8 a3[4];
          #pragma unroll
          for (int ks = 0; ks < 4; ++ks) a3[ks] = *(const half8*)&hnxt[m*16+n16][ks*32 + quad*8];
          floatx4 facc = (floatx4){0.f,0.f,0.f,0.f};
          #pragma unroll
          for (int ks = 0; ks < 4; ++ks) facc = __builtin_amdgcn_mfma_f32_16x16x32_f16(a3[ks], __builtin_bit_cast(half8, wfc[ks]), facc, 0,0,0);
          #pragma unroll
          for (int rr = 0; rr < 4; ++rr){
            const int row = m*16 + quad*4 + rr;
            float v = facc[rr] + fcb_j;
            fcout[row][j] = (_Float16)v;          // cols 48..63 stay zero
            if (j < IN_D)
              out[((size_t)(r0 + row)*T_LEN + t)*IN_D + j] = v;
          }
        }
      }
      __syncthreads();
      if (tid < 256){
        int* odst = (int*)(oring + (((size_t)(t&3))*BATCH + r0)*64);
        st_ring_x4(odst + my4, *(const int4v*)&fcout[my4>>5][(my4&31)*2]);
      }
    }
    _Float16 (*tmp)[136] = hcur; hcur = hnxt; hnxt = tmp;
  }
  drain_vm();
}

extern "C" void kernel_launch(void* const* d_in, const int* in_sizes, int n_in,
                              void* d_out, int out_size, void* d_ws, size_t ws_size,
                              hipStream_t stream)
{
  const float* x        = (const float*)d_in[0];
  const float* enc_Wih0 = (const float*)d_in[2];
  const float* enc_WihR = (const float*)d_in[3];
  const float* enc_Whh  = (const float*)d_in[4];
  const float* enc_b    = (const float*)d_in[5];
  const float* dec_Wih0 = (const float*)d_in[6];
  const float* dec_WihR = (const float*)d_in[7];
  const float* dec_Whh  = (const float*)d_in[8];
  const float* dec_b    = (const float*)d_in[9];
  const float* fc_W     = (const float*)d_in[10];
  const float* fc_b     = (const float*)d_in[11];

  char* ws = (char*)d_ws;
  _Float16* encw   = (_Float16*)(ws + OFF_ENCW);
  _Float16* decw   = (_Float16*)(ws + OFF_DECW);
  _Float16* ring_e = (_Float16*)(ws + OFF_RING_E);
  _Float16* ring_d = (_Float16*)(ws + OFF_RING_D);
  _Float16* oring  = (_Float16*)(ws + OFF_ORING);
  _Float16* h_enc  = (_Float16*)(ws + OFF_HENC);
  float*    c_enc  = (float*)(ws + OFF_CENC);
  int*      flags  = (int*)(ws + OFF_FLAGS);
  int*      rings  = (int*)(ws + OFF_RING_E);
  float*    outp   = (float*)d_out;

  prep_weights<<<4096, 256, 0, stream>>>(enc_Wih0, enc_WihR, enc_Whh,
                                         dec_Wih0, dec_WihR, dec_Whh, fc_W,
                                         encw, decw, rings, flags);
  enc_pipe<<<256, 512, 0, stream>>>(x, encw, enc_b, ring_e, h_enc, c_enc, flags);
  dec_pipe<<<256, 512, 0, stream>>>(x, decw, dec_b, fc_b, ring_d, oring,
                                    h_enc, c_enc, flags, outp);
}

// Round 5
// 1301.009 us; speedup vs baseline: 1.1184x; 1.1008x over previous
//
#include <hip/hip_runtime.h>
#include <hip/hip_bf16.h>
#include <cstdint>
#include <cstddef>

typedef _Float16 half8  __attribute__((ext_vector_type(8)));
typedef float    floatx4 __attribute__((ext_vector_type(4)));
typedef int      int4v   __attribute__((ext_vector_type(4)));

#define S_LEN 200
#define BATCH 2048
#define HID   128
#define T_LEN 50
#define IN_D  44

// Sentinel: two f16 NaNs. h/FC values are finite => data dword never equals it.
#define SENT32 0x7E007E00

// ---- workspace byte offsets ----
#define OFF_ENCW   0ull
#define OFF_DECW   983040ull
#define OFF_RING_E 1978368ull    // [3][8][2048][128] f16 = 12,582,912 B
#define OFF_RING_D 14561280ull   // [3][4][2048][128] f16 = 6,291,456 B
#define OFF_ORING  20852736ull   // [4][2048][64] f16 = 1,048,576 B
#define OFF_HENC   21901312ull   // [4][2048][128] f16 = 2,097,152 B
#define OFF_CENC   23998464ull   // [4][2048][128] f32 = 4,194,304 B
#define OFF_FLAGS  28192768ull   // int[1024*32]: flag i at [i*32]
// rings contiguous: 19,922,944 B = 4,980,736 dwords

#define SCOPE_AGENT __HIP_MEMORY_SCOPE_AGENT

#define LOG2E  1.44269504f
#define LOG2E2 2.88539008f
__device__ __forceinline__ float sigf(float x){
  float e = __builtin_amdgcn_exp2f(-LOG2E * x);
  return __builtin_amdgcn_rcpf(1.f + e);
}
__device__ __forceinline__ float tanhf_fast(float x){
  float e = __builtin_amdgcn_exp2f(LOG2E2 * x);
  return 1.f - 2.f * __builtin_amdgcn_rcpf(e + 1.f);
}

__device__ __forceinline__ int  ldc(const int* p){ return __hip_atomic_load(p, __ATOMIC_RELAXED, SCOPE_AGENT); }
__device__ __forceinline__ void stc(int* p, int v){ __hip_atomic_store(p, v, __ATOMIC_RELAXED, SCOPE_AGENT); }
__device__ __forceinline__ void drain_vm(){ asm volatile("s_waitcnt vmcnt(0)" ::: "memory"); }
__device__ __forceinline__ int* flagp(int* flags, int idx){ return flags + idx*32; }

// ---- self-contained x4 fabric ops (sc0 sc1 = L1/L2 bypass, MALL-coherent).
// Load embeds its own vmcnt(0): value is architecturally valid at asm exit —
// no issue-only register hazard. Validated correct in round 3 (decoder).
__device__ __forceinline__ int4v ld_ring_x4(const int* p){
  int4v r;
  asm volatile("global_load_dwordx4 %0, %1, off sc0 sc1\n\t"
               "s_waitcnt vmcnt(0)"
               : "=v"(r) : "v"(p) : "memory");
  return r;
}
__device__ __forceinline__ void st_ring_x4(int* p, int4v v){
  asm volatile("global_store_dwordx4 %0, %1, off sc0 sc1"
               :: "v"(p), "v"(v) : "memory");
}
__device__ __forceinline__ bool any_sent(int4v v){
  return (v.x==SENT32)||(v.y==SENT32)||(v.z==SENT32)||(v.w==SENT32);
}

#define PIN(v) asm volatile("" : "+v"(v))

__global__ void prep_weights(const float* __restrict__ eW0, const float* __restrict__ eWR,
                             const float* __restrict__ eWH, const float* __restrict__ dW0,
                             const float* __restrict__ dWR, const float* __restrict__ dWH,
                             const float* __restrict__ fcW,
                             _Float16* __restrict__ encw, _Float16* __restrict__ decw,
                             int* __restrict__ rings, int* __restrict__ flags)
{
  int i = blockIdx.x*256 + threadIdx.x;
  if (i < 491520) {
    _Float16 v;
    if (i < 32768)      { int j=i>>6, k=i&63; v = (k<IN_D)? (_Float16)eW0[j*IN_D+k] : (_Float16)0.f; }
    else if (i < 229376){ v = (_Float16)eWR[i-32768]; }
    else                { v = (_Float16)eWH[i-229376]; }
    encw[i] = v;
  }
  if (i < 497664) {
    _Float16 v;
    if (i < 32768)      { int j=i>>6, k=i&63; v = (k<IN_D)? (_Float16)dW0[j*IN_D+k] : (_Float16)0.f; }
    else if (i < 229376){ v = (_Float16)dWR[i-32768]; }
    else if (i < 491520){ v = (_Float16)dWH[i-229376]; }
    else { int r=i-491520; int j=r>>7, k=r&127; v = (j<IN_D)? (_Float16)fcW[j*HID+k] : (_Float16)0.f; }
    decw[i] = v;
  }
  for (int j = i; j < 4980736; j += 4096*256) rings[j] = SENT32;  // sentinel-fill all rings
  if (i < 32768) flags[i] = 0;
}

// ============================================================================
// Encoder, TSTEP=2: each block processes TWO consecutive timesteps per
// handoff (recurrence is block-internal), halving the per-step handoff
// overhead (poll RT + store-ack drains + visibility lag). Ring bytes are
// IDENTICAL to baseline ((2q+p)&7 == (q&3)*2+p); the proven protocol is
// re-indexed to double-steps q (100 of them): 4 double-slots, cflag counts
// dsteps, producer gate seen >= q-3. Polls/resets/publishes use the
// round-3-validated x4 asm ops. Both planes are polled BEFORE any reset
// store so the second poll's embedded vmcnt(0) never waits a store ack.
// ============================================================================

__global__ __launch_bounds__(512, 2)
void enc_pipe(const float* __restrict__ x, const _Float16* __restrict__ encw,
              const float* __restrict__ enc_b, _Float16* __restrict__ ring,
              _Float16* __restrict__ h_enc, float* __restrict__ c_enc,
              int* __restrict__ flags)
{
  const int tid = threadIdx.x;
  const int w = tid >> 6, lane = tid & 63, quad = lane >> 4, n16 = lane & 15;
  const int l = blockIdx.x >> 6, s = blockIdx.x & 63, r0 = s * 32;
  const int u = w*16 + n16;
  const int KSI = (l == 0) ? 2 : 4;
  const int my4 = tid*4;

  __shared__ _Float16 xb[2][32][136];   // two input planes (sub-steps)
  __shared__ _Float16 hA[32][136];      // h at dstep start; sub1 writes here
  __shared__ _Float16 hB[32][136];      // sub0 output (plane-0 h)

  for (int i = tid; i < 32*136; i += 512){
    ((_Float16*)xb[0])[i] = (_Float16)0.f;
    ((_Float16*)xb[1])[i] = (_Float16)0.f;
    ((_Float16*)hA)[i] = (_Float16)0.f;
    ((_Float16*)hB)[i] = (_Float16)0.f;
  }

  const _Float16* Wi = (l==0) ? encw : encw + 32768 + (size_t)(l-1)*65536;
  const _Float16* Wh = encw + 229376 + (size_t)l*65536;
  const int KI = KSI * 32;
  floatx4 wfi[4][4], wfh[4][4];
  #pragma unroll
  for (int nt = 0; nt < 4; ++nt){
    const int grow = nt*128 + u;
    #pragma unroll
    for (int ks = 0; ks < 4; ++ks){
      if (ks < KSI){ wfi[nt][ks] = *(const floatx4*)(Wi + (size_t)grow*KI + ks*32 + quad*8); PIN(wfi[nt][ks]); }
      wfh[nt][ks] = *(const floatx4*)(Wh + (size_t)grow*HID + ks*32 + quad*8); PIN(wfh[nt][ks]);
    }
  }
  float breg[4];
  #pragma unroll
  for (int g = 0; g < 4; ++g) breg[g] = enc_b[l*512 + g*128 + u];
  float creg[2][4] = {{0.f,0.f,0.f,0.f},{0.f,0.f,0.f,0.f}};

  // layer-0 x prefetch: 2 planes x 3 elems/thread (covers 32*44=1408)
  int xr_r[3], xr_k[3]; bool xr_v[3]; float xr[2][3];
  if (l == 0){
    #pragma unroll
    for (int j = 0; j < 3; ++j){
      int idx = tid + j*512; xr_v[j] = idx < 32*IN_D;
      xr_r[j] = xr_v[j] ? idx / IN_D : 0; xr_k[j] = xr_v[j] ? idx % IN_D : 0;
      #pragma unroll
      for (int p = 0; p < 2; ++p)
        xr[p][j] = xr_v[j] ? x[((size_t)(r0+xr_r[j])*S_LEN + p)*IN_D + xr_k[j]] : 0.f;
    }
  }

  int* cflag_self = flagp(flags, l*64 + s);        // published by l>=1 (dsteps)
  int* cflag_next = flagp(flags, (l+1)*64 + s);    // read by l<3 (backpressure)
  int seen_cons = 0;

  // cell: one LSTM sub-step on (xin, hin) -> hout; creg[m][rr] carried.
  auto cell = [&](const _Float16 (*xin)[136], const _Float16 (*hin)[136],
                  _Float16 (*hout)[136], bool writeHC){
    #pragma unroll
    for (int m = 0; m < 2; ++m){
      half8 ai[4], ah[4];
      #pragma unroll
      for (int ks = 0; ks < 4; ++ks){
        if (ks < KSI) ai[ks] = *(const half8*)&xin[m*16+n16][ks*32 + quad*8];
        ah[ks] = *(const half8*)&hin[m*16+n16][ks*32 + quad*8];
      }
      floatx4 acc[4];
      #pragma unroll
      for (int nt = 0; nt < 4; ++nt){
        acc[nt] = (floatx4){0.f,0.f,0.f,0.f};
        #pragma unroll
        for (int ks = 0; ks < 4; ++ks){
          if (ks < KSI) acc[nt] = __builtin_amdgcn_mfma_f32_16x16x32_f16(ai[ks], __builtin_bit_cast(half8, wfi[nt][ks]), acc[nt], 0,0,0);
          acc[nt] = __builtin_amdgcn_mfma_f32_16x16x32_f16(ah[ks], __builtin_bit_cast(half8, wfh[nt][ks]), acc[nt], 0,0,0);
        }
      }
      #pragma unroll
      for (int rr = 0; rr < 4; ++rr){
        float ip = acc[0][rr] + breg[0];
        float fp = acc[1][rr] + breg[1];
        float gp = acc[2][rr] + breg[2];
        float op = acc[3][rr] + breg[3];
        float cc = sigf(fp)*creg[m][rr] + sigf(ip)*tanhf_fast(gp);
        float hh = sigf(op)*tanhf_fast(cc);
        creg[m][rr] = cc;
        const int row = m*16 + quad*4 + rr;
        hout[row][u] = (_Float16)hh;
        if (writeHC){
          h_enc[((size_t)l*BATCH + r0 + row)*HID + u] = (_Float16)hh;
          c_enc[((size_t)l*BATCH + r0 + row)*HID + u] = cc;
        }
      }
    }
  };

  __syncthreads();

  const int4v sv = {SENT32, SENT32, SENT32, SENT32};

  for (int q = 0; q < S_LEN/2; ++q){        // 100 double-steps; t = 2q, 2q+1
    // ---- stage inputs for both sub-steps ----
    if (l == 0){
      #pragma unroll
      for (int p = 0; p < 2; ++p)
        #pragma unroll
        for (int j = 0; j < 3; ++j)
          if (xr_v[j]) xb[p][xr_r[j]][xr_k[j]] = (_Float16)xr[p][j];
    } else {
      const int sbase = (l-1)*8 + ((q&3)<<1);
      int* s0 = (int*)(ring + ((size_t)(sbase+0)*BATCH + r0)*HID) + my4;
      int* s1 = (int*)(ring + ((size_t)(sbase+1)*BATCH + r0)*HID) + my4;
      // poll BOTH planes before any reset store (keeps embedded vmcnt(0)
      // from waiting on our own store acks)
      int4v v0 = ld_ring_x4(s0);
      while (any_sent(v0)){ __builtin_amdgcn_s_sleep(1); v0 = ld_ring_x4(s0); }
      int4v v1 = ld_ring_x4(s1);
      while (any_sent(v1)){ __builtin_amdgcn_s_sleep(1); v1 = ld_ring_x4(s1); }
      *(int4v*)&xb[0][my4>>6][(my4&63)*2] = v0;
      *(int4v*)&xb[1][my4>>6][(my4&63)*2] = v1;
      st_ring_x4(s0, sv);
      st_ring_x4(s1, sv);
    }
    // backpressure: producer gate in dsteps (4 double-slots; reuse at q+4)
    if (tid == 0 && l < 3 && q >= 4){
      while (seen_cons < q-3){
        seen_cons = ldc(cflag_next);
        if (seen_cons < q-3) __builtin_amdgcn_s_sleep(1);
      }
    }
    __syncthreads();

    // l0: prefetch next dstep's x (tracked; drained by later barriers)
    if (l == 0 && q < S_LEN/2 - 1){
      #pragma unroll
      for (int p = 0; p < 2; ++p)
        #pragma unroll
        for (int j = 0; j < 3; ++j)
          if (xr_v[j]) xr[p][j] = x[((size_t)(r0+xr_r[j])*S_LEN + (2*q+2+p))*IN_D + xr_k[j]];
    }

    // ---- sub-step 0: xb[0], hA -> hB ----
    cell(xb[0], hA, hB, false);
    __syncthreads();
    // ---- sub-step 1: xb[1], hB -> hA ----
    cell(xb[1], hB, hA, (q == S_LEN/2 - 1));
    __syncthreads();

    // consumed-flag publish (resets had 2 compute phases + barriers to land;
    // barrier's vmcnt(0) + drain_vm make it airtight for all waves)
    if (l > 0){
      drain_vm();
      if (tid == 0) stc(cflag_self, q+1);
    }
    // ---- publish both h planes: data IS the flag ----
    if (l < 3){
      const int dbase = l*8 + ((q&3)<<1);
      int* d0p = (int*)(ring + ((size_t)(dbase+0)*BATCH + r0)*HID) + my4;
      int* d1p = (int*)(ring + ((size_t)(dbase+1)*BATCH + r0)*HID) + my4;
      st_ring_x4(d0p, *(const int4v*)&hB[my4>>6][(my4&63)*2]);
      st_ring_x4(d1p, *(const int4v*)&hA[my4>>6][(my4&63)*2]);
    }
  }
  drain_vm();
}

// ============================================================================
// dec_pipe: round-3 version VERBATIM (passed). Full baseline protocol —
// backpressure flags, drain_vm before consumed-flag publish — with ring
// polls/resets/publishes widened to x4 asm ops.
// ============================================================================

__global__ __launch_bounds__(512, 2)
void dec_pipe(const float* __restrict__ x, const _Float16* __restrict__ decw,
              const float* __restrict__ dec_b, const float* __restrict__ fc_b,
              _Float16* __restrict__ ring, _Float16* __restrict__ oring,
              const _Float16* __restrict__ h_enc, const float* __restrict__ c_enc,
              int* __restrict__ flags, float* __restrict__ out)
{
  const int tid = threadIdx.x;
  const int w = tid >> 6, lane = tid & 63, quad = lane >> 4, n16 = lane & 15;
  const int l = blockIdx.x >> 6, s = blockIdx.x & 63, r0 = s * 32;
  const int u = w*16 + n16;
  const int KSI = (l == 0) ? 2 : 4;
  const int my4 = tid*4;

  __shared__ _Float16 xbuf[32][136];
  __shared__ _Float16 hb[2][32][136];
  __shared__ _Float16 fcout[32][64];

  for (int i = tid; i < 32*136; i += 512) ((_Float16*)xbuf)[i] = (_Float16)0.f;
  for (int i = tid; i < 32*64; i += 512) ((_Float16*)fcout)[i] = (_Float16)0.f;

  const _Float16* Wi = (l==0) ? decw : decw + 32768 + (size_t)(l-1)*65536;
  const _Float16* Wh = decw + 229376 + (size_t)l*65536;
  const _Float16* FCW = decw + 491520;
  const int KI = KSI * 32;
  floatx4 wfi[4][4], wfh[4][4];
  #pragma unroll
  for (int nt = 0; nt < 4; ++nt){
    const int grow = nt*128 + u;
    #pragma unroll
    for (int ks = 0; ks < 4; ++ks){
      if (ks < KSI){ wfi[nt][ks] = *(const floatx4*)(Wi + (size_t)grow*KI + ks*32 + quad*8); PIN(wfi[nt][ks]); }
      wfh[nt][ks] = *(const floatx4*)(Wh + (size_t)grow*HID + ks*32 + quad*8); PIN(wfh[nt][ks]);
    }
  }
  float breg[4];
  #pragma unroll
  for (int g = 0; g < 4; ++g) breg[g] = dec_b[l*512 + g*128 + u];

  {
    int idx = tid*8, rr_ = idx >> 7, kk = idx & 127;
    *(half8*)&hb[0][rr_][kk] = *(const half8*)(h_enc + ((size_t)l*BATCH + r0)*HID + rr_*HID + kk);
  }
  float creg[2][4];
  #pragma unroll
  for (int m = 0; m < 2; ++m)
    #pragma unroll
    for (int rr = 0; rr < 4; ++rr)
      creg[m][rr] = c_enc[((size_t)l*BATCH + r0 + m*16 + quad*4 + rr)*HID + u];

  floatx4 wfc[4]; float fcb_j = 0.f;
  const int j = w*16 + n16;
  if (w < 3){
    #pragma unroll
    for (int ks = 0; ks < 4; ++ks){
      wfc[ks] = *(const floatx4*)(FCW + (size_t)j*HID + ks*32 + quad*8); PIN(wfc[ks]);
    }
    if (j < IN_D) fcb_j = fc_b[j];
  }

  int* cflag_self = flagp(flags, 256 + l*64 + s);     // published by l>=1 (ring_d)
  int* cflag_next = flagp(flags, 256 + (l+1)*64 + s); // read by l<3
  int* cflag_o    = flagp(flags, 512 + s);            // published by l0, read by l3
  int seen = 0;

  __syncthreads();

  _Float16 (*hcur)[136] = hb[0];
  _Float16 (*hnxt)[136] = hb[1];

  const int4v sv = {SENT32, SENT32, SENT32, SENT32};

  for (int t = 0; t < T_LEN; ++t){
    // ---- stage input (x4 polls, embedded vmcnt(0)) ----
    if (l == 0){
      if (t == 0){
        for (int idx = tid; idx < 32*IN_D; idx += 512){
          int r = idx / IN_D, k = idx % IN_D;
          xbuf[r][k] = (_Float16)x[((size_t)(r0+r)*S_LEN + (S_LEN-1))*IN_D + k];
        }
      } else if (tid < 256){
        int* srcd = (int*)(oring + (((size_t)((t-1)&3))*BATCH + r0)*64);
        int4v v = ld_ring_x4(srcd + my4);
        while (any_sent(v)){
          __builtin_amdgcn_s_sleep(1);
          v = ld_ring_x4(srcd + my4);
        }
        *(int4v*)&xbuf[my4>>5][(my4&31)*2] = v;
        st_ring_x4(srcd + my4, sv);
      }
    } else {
      int* srcd = (int*)(ring + (((size_t)(l-1)*4 + (t&3))*BATCH + r0)*HID);
      int4v v = ld_ring_x4(srcd + my4);
      while (any_sent(v)){
        __builtin_amdgcn_s_sleep(1);
        v = ld_ring_x4(srcd + my4);
      }
      *(int4v*)&xbuf[my4>>6][(my4&63)*2] = v;
      st_ring_x4(srcd + my4, sv);
    }
    // backpressure (slow path) — exact baseline
    if (tid == 0 && t >= 4){
      if (l < 3){
        while (seen < t-3){ seen = ldc(cflag_next); if (seen < t-3) __builtin_amdgcn_s_sleep(1); }
      } else {
        while (seen < t-2){ seen = ldc(cflag_o); if (seen < t-2) __builtin_amdgcn_s_sleep(1); }
      }
    }
    __syncthreads();

    // ---- gates + cell update ----
    #pragma unroll
    for (int m = 0; m < 2; ++m){
      half8 ai[4], ah[4];
      #pragma unroll
      for (int ks = 0; ks < 4; ++ks){
        if (ks < KSI) ai[ks] = *(const half8*)&xbuf[m*16+n16][ks*32 + quad*8];
        ah[ks] = *(const half8*)&hcur[m*16+n16][ks*32 + quad*8];
      }
      floatx4 acc[4];
      #pragma unroll
      for (int nt = 0; nt < 4; ++nt){
        acc[nt] = (floatx4){0.f,0.f,0.f,0.f};
        #pragma unroll
        for (int ks = 0; ks < 4; ++ks){
          if (ks < KSI) acc[nt] = __builtin_amdgcn_mfma_f32_16x16x32_f16(ai[ks], __builtin_bit_cast(half8, wfi[nt][ks]), acc[nt], 0,0,0);
          acc[nt] = __builtin_amdgcn_mfma_f32_16x16x32_f16(ah[ks], __builtin_bit_cast(half8, wfh[nt][ks]), acc[nt], 0,0,0);
        }
      }
      #pragma unroll
      for (int rr = 0; rr < 4; ++rr){
        float ip = acc[0][rr] + breg[0];
        float fp = acc[1][rr] + breg[1];
        float gp = acc[2][rr] + breg[2];
        float op = acc[3][rr] + breg[3];
        float cc = sigf(fp)*creg[m][rr] + sigf(ip)*tanhf_fast(gp);
        float hh = sigf(op)*tanhf_fast(cc);
        creg[m][rr] = cc;
        hnxt[m*16 + quad*4 + rr][u] = (_Float16)hh;
      }
    }
    __syncthreads();

    // consumed-flag publish — drain covers asm resets (HW vmcnt counter)
    drain_vm();
    if (tid == 0){
      if (l > 0) stc(cflag_self, t+1);
      else if (t > 0) stc(cflag_o, t+1);
    }

    if (l < 3){
      int* dst = (int*)(ring + (((size_t)l*4 + (t&3))*BATCH + r0)*HID);
      st_ring_x4(dst + my4, *(const int4v*)&hnxt[my4>>6][(my4&63)*2]);
    } else {
      // ---- FC + output + feedback (waves 0..2 cover cols 0..47) ----
      if (w < 3){
        #pragma unroll
        for (int m = 0; m < 2; ++m){
          half8 a3[4];
          #pragma unroll
          for (int ks = 0; ks < 4; ++ks) a3[ks] = *(const half8*)&hnxt[m*16+n16][ks*32 + quad*8];
          floatx4 facc = (floatx4){0.f,0.f,0.f,0.f};
          #pragma unroll
          for (int ks = 0; ks < 4; ++ks) facc = __builtin_amdgcn_mfma_f32_16x16x32_f16(a3[ks], __builtin_bit_cast(half8, wfc[ks]), facc, 0,0,0);
          #pragma unroll
          for (int rr = 0; rr < 4; ++rr){
            const int row = m*16 + quad*4 + rr;
            float v = facc[rr] + fcb_j;
            fcout[row][j] = (_Float16)v;          // cols 48..63 stay zero
            if (j < IN_D)
              out[((size_t)(r0 + row)*T_LEN + t)*IN_D + j] = v;
          }
        }
      }
      __syncthreads();
      if (tid < 256){
        int* odst = (int*)(oring + (((size_t)(t&3))*BATCH + r0)*64);
        st_ring_x4(odst + my4, *(const int4v*)&fcout[my4>>5][(my4&31)*2]);
      }
    }
    _Float16 (*tmp)[136] = hcur; hcur = hnxt; hnxt = tmp;
  }
  drain_vm();
}

extern "C" void kernel_launch(void* const* d_in, const int* in_sizes, int n_in,
                              void* d_out, int out_size, void* d_ws, size_t ws_size,
                              hipStream_t stream)
{
  const float* x        = (const float*)d_in[0];
  const float* enc_Wih0 = (const float*)d_in[2];
  const float* enc_WihR = (const float*)d_in[3];
  const float* enc_Whh  = (const float*)d_in[4];
  const float* enc_b    = (const float*)d_in[5];
  const float* dec_Wih0 = (const float*)d_in[6];
  const float* dec_WihR = (const float*)d_in[7];
  const float* dec_Whh  = (const float*)d_in[8];
  const float* dec_b    = (const float*)d_in[9];
  const float* fc_W     = (const float*)d_in[10];
  const float* fc_b     = (const float*)d_in[11];

  char* ws = (char*)d_ws;
  _Float16* encw   = (_Float16*)(ws + OFF_ENCW);
  _Float16* decw   = (_Float16*)(ws + OFF_DECW);
  _Float16* ring_e = (_Float16*)(ws + OFF_RING_E);
  _Float16* ring_d = (_Float16*)(ws + OFF_RING_D);
  _Float16* oring  = (_Float16*)(ws + OFF_ORING);
  _Float16* h_enc  = (_Float16*)(ws + OFF_HENC);
  float*    c_enc  = (float*)(ws + OFF_CENC);
  int*      flags  = (int*)(ws + OFF_FLAGS);
  int*      rings  = (int*)(ws + OFF_RING_E);
  float*    outp   = (float*)d_out;

  prep_weights<<<4096, 256, 0, stream>>>(enc_Wih0, enc_WihR, enc_Whh,
                                         dec_Wih0, dec_WihR, dec_Whh, fc_W,
                                         encw, decw, rings, flags);
  enc_pipe<<<256, 512, 0, stream>>>(x, encw, enc_b, ring_e, h_enc, c_enc, flags);
  dec_pipe<<<256, 512, 0, stream>>>(x, decw, dec_b, fc_b, ring_d, oring,
                                    h_enc, c_enc, flags, outp);
}

// Round 8
// 1274.284 us; speedup vs baseline: 1.1419x; 1.0210x over previous
//
#include <hip/hip_runtime.h>
#include <hip/hip_bf16.h>
#include <cstdint>
#include <cstddef>

typedef _Float16 half8  __attribute__((ext_vector_type(8)));
typedef float    floatx4 __attribute__((ext_vector_type(4)));
typedef int      int4v   __attribute__((ext_vector_type(4)));

#define S_LEN 200
#define BATCH 2048
#define HID   128
#define T_LEN 50
#define IN_D  44

// Sentinel: two f16 NaNs. h/FC values are finite => data dword never equals it.
#define SENT32 0x7E007E00

// ---- workspace byte offsets ----
#define OFF_ENCW   0ull
#define OFF_DECW   983040ull
#define OFF_RING_E 1978368ull    // [3][8][2048][128] f16 = 12,582,912 B
#define OFF_RING_D 14561280ull   // [3][4][2048][128] f16 = 6,291,456 B
#define OFF_ORING  20852736ull   // [4][2048][64] f16 = 1,048,576 B
#define OFF_HENC   21901312ull   // [4][2048][128] f16 = 2,097,152 B
#define OFF_CENC   23998464ull   // [4][2048][128] f32 = 4,194,304 B
#define OFF_FLAGS  28192768ull   // int[1024*32]: flag i at [i*32]
// rings contiguous: 19,922,944 B = 4,980,736 dwords

#define SCOPE_AGENT __HIP_MEMORY_SCOPE_AGENT

#define LOG2E  1.44269504f
#define LOG2E2 2.88539008f
__device__ __forceinline__ float sigf(float x){
  float e = __builtin_amdgcn_exp2f(-LOG2E * x);
  return __builtin_amdgcn_rcpf(1.f + e);
}
__device__ __forceinline__ float tanhf_fast(float x){
  float e = __builtin_amdgcn_exp2f(LOG2E2 * x);
  return 1.f - 2.f * __builtin_amdgcn_rcpf(e + 1.f);
}

__device__ __forceinline__ int  ldc(const int* p){ return __hip_atomic_load(p, __ATOMIC_RELAXED, SCOPE_AGENT); }
__device__ __forceinline__ void stc(int* p, int v){ __hip_atomic_store(p, v, __ATOMIC_RELAXED, SCOPE_AGENT); }
__device__ __forceinline__ void drain_vm(){ asm volatile("s_waitcnt vmcnt(0)" ::: "memory"); }
__device__ __forceinline__ int* flagp(int* flags, int idx){ return flags + idx*32; }

// ---- self-contained fabric ops (sc0 sc1 = L1/L2 bypass, MALL-coherent).
// Loads embed their own vmcnt(0): values architecturally valid at asm exit.
__device__ __forceinline__ int4v ld_ring_x4(const int* p){
  int4v r;
  asm volatile("global_load_dwordx4 %0, %1, off sc0 sc1\n\t"
               "s_waitcnt vmcnt(0)"
               : "=v"(r) : "v"(p) : "memory");
  return r;
}
// Fused 2-plane poll: both loads in flight together, ONE wait (2 RTs in
// parallel instead of serial). Early-clobber outputs keep the loads from
// clobbering the other plane's address registers. (Half the register
// footprint of the condemned 4-plane variant.)
__device__ __forceinline__ void ld_ring_x4x2(int4v &r0, int4v &r1,
                                             const int* p0, const int* p1){
  asm volatile("global_load_dwordx4 %0, %2, off sc0 sc1\n\t"
               "global_load_dwordx4 %1, %3, off sc0 sc1\n\t"
               "s_waitcnt vmcnt(0)"
               : "=&v"(r0), "=&v"(r1)
               : "v"(p0), "v"(p1)
               : "memory");
}
__device__ __forceinline__ void st_ring_x4(int* p, int4v v){
  asm volatile("global_store_dwordx4 %0, %1, off sc0 sc1"
               :: "v"(p), "v"(v) : "memory");
}
__device__ __forceinline__ bool any_sent(int4v v){
  return (v.x==SENT32)||(v.y==SENT32)||(v.z==SENT32)||(v.w==SENT32);
}

#define PIN(v) asm volatile("" : "+v"(v))

__global__ void prep_weights(const float* __restrict__ eW0, const float* __restrict__ eWR,
                             const float* __restrict__ eWH, const float* __restrict__ dW0,
                             const float* __restrict__ dWR, const float* __restrict__ dWH,
                             const float* __restrict__ fcW,
                             _Float16* __restrict__ encw, _Float16* __restrict__ decw,
                             int* __restrict__ rings, int* __restrict__ flags)
{
  int i = blockIdx.x*256 + threadIdx.x;
  if (i < 491520) {
    _Float16 v;
    if (i < 32768)      { int j=i>>6, k=i&63; v = (k<IN_D)? (_Float16)eW0[j*IN_D+k] : (_Float16)0.f; }
    else if (i < 229376){ v = (_Float16)eWR[i-32768]; }
    else                { v = (_Float16)eWH[i-229376]; }
    encw[i] = v;
  }
  if (i < 497664) {
    _Float16 v;
    if (i < 32768)      { int j=i>>6, k=i&63; v = (k<IN_D)? (_Float16)dW0[j*IN_D+k] : (_Float16)0.f; }
    else if (i < 229376){ v = (_Float16)dWR[i-32768]; }
    else if (i < 491520){ v = (_Float16)dWH[i-229376]; }
    else { int r=i-491520; int j=r>>7, k=r&127; v = (j<IN_D)? (_Float16)fcW[j*HID+k] : (_Float16)0.f; }
    decw[i] = v;
  }
  for (int j = i; j < 4980736; j += 4096*256) rings[j] = SENT32;  // sentinel-fill all rings
  if (i < 32768) flags[i] = 0;
}

// ============================================================================
// Encoder, TSTEP=2 (base = the 1301 µs passing kernel) with two minimal
// deltas: (1) fused 2-plane poll (one parallel RT instead of two serial);
// (2) plane-0 publish pipelined under sub-step 1's compute. Ring bytes
// identical to baseline ((2q+p)&7 == (q&3)*2+p): 4 double-slots, cflag in
// dsteps, producer gate seen >= q-3 (slot reuse at q+4).
// ============================================================================

__global__ __launch_bounds__(512, 2)
void enc_pipe(const float* __restrict__ x, const _Float16* __restrict__ encw,
              const float* __restrict__ enc_b, _Float16* __restrict__ ring,
              _Float16* __restrict__ h_enc, float* __restrict__ c_enc,
              int* __restrict__ flags)
{
  const int tid = threadIdx.x;
  const int w = tid >> 6, lane = tid & 63, quad = lane >> 4, n16 = lane & 15;
  const int l = blockIdx.x >> 6, s = blockIdx.x & 63, r0 = s * 32;
  const int u = w*16 + n16;
  const int KSI = (l == 0) ? 2 : 4;
  const int my4 = tid*4;

  __shared__ _Float16 xb[2][32][136];   // two input planes (sub-steps)
  __shared__ _Float16 hA[32][136];      // h at dstep start; sub1 writes here
  __shared__ _Float16 hB[32][136];      // sub0 output (plane-0 h)

  for (int i = tid; i < 32*136; i += 512){
    ((_Float16*)xb[0])[i] = (_Float16)0.f;
    ((_Float16*)xb[1])[i] = (_Float16)0.f;
    ((_Float16*)hA)[i] = (_Float16)0.f;
    ((_Float16*)hB)[i] = (_Float16)0.f;
  }

  const _Float16* Wi = (l==0) ? encw : encw + 32768 + (size_t)(l-1)*65536;
  const _Float16* Wh = encw + 229376 + (size_t)l*65536;
  const int KI = KSI * 32;
  floatx4 wfi[4][4], wfh[4][4];
  #pragma unroll
  for (int nt = 0; nt < 4; ++nt){
    const int grow = nt*128 + u;
    #pragma unroll
    for (int ks = 0; ks < 4; ++ks){
      if (ks < KSI){ wfi[nt][ks] = *(const floatx4*)(Wi + (size_t)grow*KI + ks*32 + quad*8); PIN(wfi[nt][ks]); }
      wfh[nt][ks] = *(const floatx4*)(Wh + (size_t)grow*HID + ks*32 + quad*8); PIN(wfh[nt][ks]);
    }
  }
  float breg[4];
  #pragma unroll
  for (int g = 0; g < 4; ++g) breg[g] = enc_b[l*512 + g*128 + u];
  float creg[2][4] = {{0.f,0.f,0.f,0.f},{0.f,0.f,0.f,0.f}};

  // layer-0 x prefetch: 2 planes x 3 elems/thread (covers 32*44=1408)
  int xr_r[3], xr_k[3]; bool xr_v[3]; float xr[2][3];
  if (l == 0){
    #pragma unroll
    for (int j = 0; j < 3; ++j){
      int idx = tid + j*512; xr_v[j] = idx < 32*IN_D;
      xr_r[j] = xr_v[j] ? idx / IN_D : 0; xr_k[j] = xr_v[j] ? idx % IN_D : 0;
      #pragma unroll
      for (int p = 0; p < 2; ++p)
        xr[p][j] = xr_v[j] ? x[((size_t)(r0+xr_r[j])*S_LEN + p)*IN_D + xr_k[j]] : 0.f;
    }
  }

  int* cflag_self = flagp(flags, l*64 + s);        // published by l>=1 (dsteps)
  int* cflag_next = flagp(flags, (l+1)*64 + s);    // read by l<3 (backpressure)
  int seen_cons = 0;

  // cell: one LSTM sub-step on (xin, hin) -> hout; creg[m][rr] carried.
  auto cell = [&](const _Float16 (*xin)[136], const _Float16 (*hin)[136],
                  _Float16 (*hout)[136], bool writeHC){
    #pragma unroll
    for (int m = 0; m < 2; ++m){
      half8 ai[4], ah[4];
      #pragma unroll
      for (int ks = 0; ks < 4; ++ks){
        if (ks < KSI) ai[ks] = *(const half8*)&xin[m*16+n16][ks*32 + quad*8];
        ah[ks] = *(const half8*)&hin[m*16+n16][ks*32 + quad*8];
      }
      floatx4 acc[4];
      #pragma unroll
      for (int nt = 0; nt < 4; ++nt){
        acc[nt] = (floatx4){0.f,0.f,0.f,0.f};
        #pragma unroll
        for (int ks = 0; ks < 4; ++ks){
          if (ks < KSI) acc[nt] = __builtin_amdgcn_mfma_f32_16x16x32_f16(ai[ks], __builtin_bit_cast(half8, wfi[nt][ks]), acc[nt], 0,0,0);
          acc[nt] = __builtin_amdgcn_mfma_f32_16x16x32_f16(ah[ks], __builtin_bit_cast(half8, wfh[nt][ks]), acc[nt], 0,0,0);
        }
      }
      #pragma unroll
      for (int rr = 0; rr < 4; ++rr){
        float ip = acc[0][rr] + breg[0];
        float fp = acc[1][rr] + breg[1];
        float gp = acc[2][rr] + breg[2];
        float op = acc[3][rr] + breg[3];
        float cc = sigf(fp)*creg[m][rr] + sigf(ip)*tanhf_fast(gp);
        float hh = sigf(op)*tanhf_fast(cc);
        creg[m][rr] = cc;
        const int row = m*16 + quad*4 + rr;
        hout[row][u] = (_Float16)hh;
        if (writeHC){
          h_enc[((size_t)l*BATCH + r0 + row)*HID + u] = (_Float16)hh;
          c_enc[((size_t)l*BATCH + r0 + row)*HID + u] = cc;
        }
      }
    }
  };

  __syncthreads();

  const int4v sv = {SENT32, SENT32, SENT32, SENT32};

  for (int q = 0; q < S_LEN/2; ++q){        // 100 double-steps; t = 2q, 2q+1
    // ---- stage inputs for both sub-steps ----
    if (l == 0){
      #pragma unroll
      for (int p = 0; p < 2; ++p)
        #pragma unroll
        for (int j = 0; j < 3; ++j)
          if (xr_v[j]) xb[p][xr_r[j]][xr_k[j]] = (_Float16)xr[p][j];
    } else {
      const int sbase = (l-1)*8 + ((q&3)<<1);
      int* s0 = (int*)(ring + ((size_t)(sbase+0)*BATCH + r0)*HID) + my4;
      int* s1 = (int*)(ring + ((size_t)(sbase+1)*BATCH + r0)*HID) + my4;
      int4v v0, v1;
      ld_ring_x4x2(v0, v1, s0, s1);           // one parallel RT for both planes
      // cold paths: per-plane re-poll (embedded vmcnt(0) each)
      while (any_sent(v0)){ __builtin_amdgcn_s_sleep(1); v0 = ld_ring_x4(s0); }
      while (any_sent(v1)){ __builtin_amdgcn_s_sleep(1); v1 = ld_ring_x4(s1); }
      *(int4v*)&xb[0][my4>>6][(my4&63)*2] = v0;
      *(int4v*)&xb[1][my4>>6][(my4&63)*2] = v1;
      st_ring_x4(s0, sv);
      st_ring_x4(s1, sv);
    }
    // backpressure: producer gate in dsteps (4 double-slots; reuse at q+4)
    if (tid == 0 && l < 3 && q >= 4){
      while (seen_cons < q-3){
        seen_cons = ldc(cflag_next);
        if (seen_cons < q-3) __builtin_amdgcn_s_sleep(1);
      }
    }
    __syncthreads();

    // l0: prefetch next dstep's x (tracked; drained by later barriers)
    if (l == 0 && q < S_LEN/2 - 1){
      #pragma unroll
      for (int p = 0; p < 2; ++p)
        #pragma unroll
        for (int j = 0; j < 3; ++j)
          if (xr_v[j]) xr[p][j] = x[((size_t)(r0+xr_r[j])*S_LEN + (2*q+2+p))*IN_D + xr_k[j]];
    }

    // ---- sub-step 0: xb[0], hA -> hB ----
    cell(xb[0], hA, hB, false);
    __syncthreads();
    // plane-0 publish pipelined under sub-step 1's compute (slot free: gate
    // covers reuse from dstep q-4; hB stable until next dstep's sub0)
    if (l < 3){
      const int dbase = l*8 + ((q&3)<<1);
      int* d0p = (int*)(ring + ((size_t)(dbase+0)*BATCH + r0)*HID) + my4;
      st_ring_x4(d0p, *(const int4v*)&hB[my4>>6][(my4&63)*2]);
    }
    // ---- sub-step 1: xb[1], hB -> hA ----
    cell(xb[1], hB, hA, (q == S_LEN/2 - 1));
    __syncthreads();

    // consumed-flag publish (resets had 2 compute phases + barriers to land)
    if (l > 0){
      drain_vm();
      if (tid == 0) stc(cflag_self, q+1);
    }
    // ---- publish plane 1: data IS the flag ----
    if (l < 3){
      const int dbase = l*8 + ((q&3)<<1);
      int* d1p = (int*)(ring + ((size_t)(dbase+1)*BATCH + r0)*HID) + my4;
      st_ring_x4(d1p, *(const int4v*)&hA[my4>>6][(my4&63)*2]);
    }
  }
  drain_vm();
}

// ============================================================================
// dec_pipe: round-3/4 version VERBATIM (passed twice). Full baseline
// protocol — backpressure flags, drain_vm before consumed-flag publish —
// with ring polls/resets/publishes widened to x4 asm ops.
// ============================================================================

__global__ __launch_bounds__(512, 2)
void dec_pipe(const float* __restrict__ x, const _Float16* __restrict__ decw,
              const float* __restrict__ dec_b, const float* __restrict__ fc_b,
              _Float16* __restrict__ ring, _Float16* __restrict__ oring,
              const _Float16* __restrict__ h_enc, const float* __restrict__ c_enc,
              int* __restrict__ flags, float* __restrict__ out)
{
  const int tid = threadIdx.x;
  const int w = tid >> 6, lane = tid & 63, quad = lane >> 4, n16 = lane & 15;
  const int l = blockIdx.x >> 6, s = blockIdx.x & 63, r0 = s * 32;
  const int u = w*16 + n16;
  const int KSI = (l == 0) ? 2 : 4;
  const int my4 = tid*4;

  __shared__ _Float16 xbuf[32][136];
  __shared__ _Float16 hb[2][32][136];
  __shared__ _Float16 fcout[32][64];

  for (int i = tid; i < 32*136; i += 512) ((_Float16*)xbuf)[i] = (_Float16)0.f;
  for (int i = tid; i < 32*64; i += 512) ((_Float16*)fcout)[i] = (_Float16)0.f;

  const _Float16* Wi = (l==0) ? decw : decw + 32768 + (size_t)(l-1)*65536;
  const _Float16* Wh = decw + 229376 + (size_t)l*65536;
  const _Float16* FCW = decw + 491520;
  const int KI = KSI * 32;
  floatx4 wfi[4][4], wfh[4][4];
  #pragma unroll
  for (int nt = 0; nt < 4; ++nt){
    const int grow = nt*128 + u;
    #pragma unroll
    for (int ks = 0; ks < 4; ++ks){
      if (ks < KSI){ wfi[nt][ks] = *(const floatx4*)(Wi + (size_t)grow*KI + ks*32 + quad*8); PIN(wfi[nt][ks]); }
      wfh[nt][ks] = *(const floatx4*)(Wh + (size_t)grow*HID + ks*32 + quad*8); PIN(wfh[nt][ks]);
    }
  }
  float breg[4];
  #pragma unroll
  for (int g = 0; g < 4; ++g) breg[g] = dec_b[l*512 + g*128 + u];

  {
    int idx = tid*8, rr_ = idx >> 7, kk = idx & 127;
    *(half8*)&hb[0][rr_][kk] = *(const half8*)(h_enc + ((size_t)l*BATCH + r0)*HID + rr_*HID + kk);
  }
  float creg[2][4];
  #pragma unroll
  for (int m = 0; m < 2; ++m)
    #pragma unroll
    for (int rr = 0; rr < 4; ++rr)
      creg[m][rr] = c_enc[((size_t)l*BATCH + r0 + m*16 + quad*4 + rr)*HID + u];

  floatx4 wfc[4]; float fcb_j = 0.f;
  const int j = w*16 + n16;
  if (w < 3){
    #pragma unroll
    for (int ks = 0; ks < 4; ++ks){
      wfc[ks] = *(const floatx4*)(FCW + (size_t)j*HID + ks*32 + quad*8); PIN(wfc[ks]);
    }
    if (j < IN_D) fcb_j = fc_b[j];
  }

  int* cflag_self = flagp(flags, 256 + l*64 + s);     // published by l>=1 (ring_d)
  int* cflag_next = flagp(flags, 256 + (l+1)*64 + s); // read by l<3
  int* cflag_o    = flagp(flags, 512 + s);            // published by l0, read by l3
  int seen = 0;

  __syncthreads();

  _Float16 (*hcur)[136] = hb[0];
  _Float16 (*hnxt)[136] = hb[1];

  const int4v sv = {SENT32, SENT32, SENT32, SENT32};

  for (int t = 0; t < T_LEN; ++t){
    // ---- stage input (x4 polls, embedded vmcnt(0)) ----
    if (l == 0){
      if (t == 0){
        for (int idx = tid; idx < 32*IN_D; idx += 512){
          int r = idx / IN_D, k = idx % IN_D;
          xbuf[r][k] = (_Float16)x[((size_t)(r0+r)*S_LEN + (S_LEN-1))*IN_D + k];
        }
      } else if (tid < 256){
        int* srcd = (int*)(oring + (((size_t)((t-1)&3))*BATCH + r0)*64);
        int4v v = ld_ring_x4(srcd + my4);
        while (any_sent(v)){
          __builtin_amdgcn_s_sleep(1);
          v = ld_ring_x4(srcd + my4);
        }
        *(int4v*)&xbuf[my4>>5][(my4&31)*2] = v;
        st_ring_x4(srcd + my4, sv);
      }
    } else {
      int* srcd = (int*)(ring + (((size_t)(l-1)*4 + (t&3))*BATCH + r0)*HID);
      int4v v = ld_ring_x4(srcd + my4);
      while (any_sent(v)){
        __builtin_amdgcn_s_sleep(1);
        v = ld_ring_x4(srcd + my4);
      }
      *(int4v*)&xbuf[my4>>6][(my4&63)*2] = v;
      st_ring_x4(srcd + my4, sv);
    }
    // backpressure (slow path) — exact baseline
    if (tid == 0 && t >= 4){
      if (l < 3){
        while (seen < t-3){ seen = ldc(cflag_next); if (seen < t-3) __builtin_amdgcn_s_sleep(1); }
      } else {
        while (seen < t-2){ seen = ldc(cflag_o); if (seen < t-2) __builtin_amdgcn_s_sleep(1); }
      }
    }
    __syncthreads();

    // ---- gates + cell update ----
    #pragma unroll
    for (int m = 0; m < 2; ++m){
      half8 ai[4], ah[4];
      #pragma unroll
      for (int ks = 0; ks < 4; ++ks){
        if (ks < KSI) ai[ks] = *(const half8*)&xbuf[m*16+n16][ks*32 + quad*8];
        ah[ks] = *(const half8*)&hcur[m*16+n16][ks*32 + quad*8];
      }
      floatx4 acc[4];
      #pragma unroll
      for (int nt = 0; nt < 4; ++nt){
        acc[nt] = (floatx4){0.f,0.f,0.f,0.f};
        #pragma unroll
        for (int ks = 0; ks < 4; ++ks){
          if (ks < KSI) acc[nt] = __builtin_amdgcn_mfma_f32_16x16x32_f16(ai[ks], __builtin_bit_cast(half8, wfi[nt][ks]), acc[nt], 0,0,0);
          acc[nt] = __builtin_amdgcn_mfma_f32_16x16x32_f16(ah[ks], __builtin_bit_cast(half8, wfh[nt][ks]), acc[nt], 0,0,0);
        }
      }
      #pragma unroll
      for (int rr = 0; rr < 4; ++rr){
        float ip = acc[0][rr] + breg[0];
        float fp = acc[1][rr] + breg[1];
        float gp = acc[2][rr] + breg[2];
        float op = acc[3][rr] + breg[3];
        float cc = sigf(fp)*creg[m][rr] + sigf(ip)*tanhf_fast(gp);
        float hh = sigf(op)*tanhf_fast(cc);
        creg[m][rr] = cc;
        hnxt[m*16 + quad*4 + rr][u] = (_Float16)hh;
      }
    }
    __syncthreads();

    // consumed-flag publish — drain covers asm resets (HW vmcnt counter)
    drain_vm();
    if (tid == 0){
      if (l > 0) stc(cflag_self, t+1);
      else if (t > 0) stc(cflag_o, t+1);
    }

    if (l < 3){
      int* dst = (int*)(ring + (((size_t)l*4 + (t&3))*BATCH + r0)*HID);
      st_ring_x4(dst + my4, *(const int4v*)&hnxt[my4>>6][(my4&63)*2]);
    } else {
      // ---- FC + output + feedback (waves 0..2 cover cols 0..47) ----
      if (w < 3){
        #pragma unroll
        for (int m = 0; m < 2; ++m){
          half8 a3[4];
          #pragma unroll
          for (int ks = 0; ks < 4; ++ks) a3[ks] = *(const half8*)&hnxt[m*16+n16][ks*32 + quad*8];
          floatx4 facc = (floatx4){0.f,0.f,0.f,0.f};
          #pragma unroll
          for (int ks = 0; ks < 4; ++ks) facc = __builtin_amdgcn_mfma_f32_16x16x32_f16(a3[ks], __builtin_bit_cast(half8, wfc[ks]), facc, 0,0,0);
          #pragma unroll
          for (int rr = 0; rr < 4; ++rr){
            const int row = m*16 + quad*4 + rr;
            float v = facc[rr] + fcb_j;
            fcout[row][j] = (_Float16)v;          // cols 48..63 stay zero
            if (j < IN_D)
              out[((size_t)(r0 + row)*T_LEN + t)*IN_D + j] = v;
          }
        }
      }
      __syncthreads();
      if (tid < 256){
        int* odst = (int*)(oring + (((size_t)(t&3))*BATCH + r0)*64);
        st_ring_x4(odst + my4, *(const int4v*)&fcout[my4>>5][(my4&31)*2]);
      }
    }
    _Float16 (*tmp)[136] = hcur; hcur = hnxt; hnxt = tmp;
  }
  drain_vm();
}

extern "C" void kernel_launch(void* const* d_in, const int* in_sizes, int n_in,
                              void* d_out, int out_size, void* d_ws, size_t ws_size,
                              hipStream_t stream)
{
  const float* x        = (const float*)d_in[0];
  const float* enc_Wih0 = (const float*)d_in[2];
  const float* enc_WihR = (const float*)d_in[3];
  const float* enc_Whh  = (const float*)d_in[4];
  const float* enc_b    = (const float*)d_in[5];
  const float* dec_Wih0 = (const float*)d_in[6];
  const float* dec_WihR = (const float*)d_in[7];
  const float* dec_Whh  = (const float*)d_in[8];
  const float* dec_b    = (const float*)d_in[9];
  const float* fc_W     = (const float*)d_in[10];
  const float* fc_b     = (const float*)d_in[11];

  char* ws = (char*)d_ws;
  _Float16* encw   = (_Float16*)(ws + OFF_ENCW);
  _Float16* decw   = (_Float16*)(ws + OFF_DECW);
  _Float16* ring_e = (_Float16*)(ws + OFF_RING_E);
  _Float16* ring_d = (_Float16*)(ws + OFF_RING_D);
  _Float16* oring  = (_Float16*)(ws + OFF_ORING);
  _Float16* h_enc  = (_Float16*)(ws + OFF_HENC);
  float*    c_enc  = (float*)(ws + OFF_CENC);
  int*      flags  = (int*)(ws + OFF_FLAGS);
  int*      rings  = (int*)(ws + OFF_RING_E);
  float*    outp   = (float*)d_out;

  prep_weights<<<4096, 256, 0, stream>>>(enc_Wih0, enc_WihR, enc_Whh,
                                         dec_Wih0, dec_WihR, dec_Whh, fc_W,
                                         encw, decw, rings, flags);
  enc_pipe<<<256, 512, 0, stream>>>(x, encw, enc_b, ring_e, h_enc, c_enc, flags);
  dec_pipe<<<256, 512, 0, stream>>>(x, decw, dec_b, fc_b, ring_d, oring,
                                    h_enc, c_enc, flags, outp);
}